// Round 6
// baseline (518.759 us; speedup 1.0000x reference)
//
#include <hip/hip_runtime.h>
#include <hip/hip_bf16.h>
#include <math.h>

// Sizes (fixed by the problem)
#define B 64
#define T 64
#define E_ENC 1024
#define EMB 512
#define D 512
#define L 32
#define S 31
#define A 512
#define V 30000
#define KSZ 7
#define KC (D * KSZ)   // 3584 = conv GEMM K

typedef __attribute__((ext_vector_type(8))) short bf16x8;
typedef __attribute__((ext_vector_type(4))) float f32x4;

__device__ __forceinline__ unsigned short f2bf(float f) {
  union { float f; unsigned int u; } x; x.f = f;
  unsigned int r = (x.u + 0x7fffu + ((x.u >> 16) & 1u)) >> 16;
  return (unsigned short)r;
}

__device__ __forceinline__ void gload_lds16(const void* g, void* l) {
  __builtin_amdgcn_global_load_lds(
      (const __attribute__((address_space(1))) unsigned int*)g,
      (__attribute__((address_space(3))) unsigned int*)l, 16, 0, 0);
}

// ---------------------------------------------------------------------------
// wv[e] = sum_a Wp[a]*Wenc[a,e];  c0 = sum_a benc[a]*Wp[a]
__global__ void k_wv(const float* __restrict__ Wenc, const float* __restrict__ Wp,
                     const float* __restrict__ benc, float* __restrict__ wv,
                     float* __restrict__ c0) {
  __shared__ float red[256];
  int e = blockIdx.x * 256 + threadIdx.x;
  float s = 0.f;
  for (int a = 0; a < A; ++a) s += Wp[a] * Wenc[(size_t)a * E_ENC + e];
  wv[e] = s;
  if (blockIdx.x == 0) {
    int t = threadIdx.x;
    float v = Wp[t] * benc[t] + Wp[t + 256] * benc[t + 256];
    red[t] = v;
    __syncthreads();
    for (int off = 128; off > 0; off >>= 1) {
      if (t < off) red[t] += red[t + off];
      __syncthreads();
    }
    if (t == 0) c0[0] = red[0];
  }
}

// ---------------------------------------------------------------------------
// Per-b: enc_mean[b,:], fscore -> softmax over t -> ctx (bf16)
__global__ void k_mean_ctx(const float* __restrict__ features, const float* __restrict__ wv,
                           const float* __restrict__ c0, float* __restrict__ enc_mean,
                           unsigned short* __restrict__ ctxb) {
  int b = blockIdx.x, tid = threadIdx.x;
  const float* fb = features + (size_t)b * T * E_ENC;
  __shared__ float s_attw[T];

  float m0 = 0, m1 = 0, m2 = 0, m3 = 0;
  for (int t = 0; t < T; ++t) {
    const float* r = fb + t * E_ENC;
    m0 += r[tid]; m1 += r[tid + 256]; m2 += r[tid + 512]; m3 += r[tid + 768];
  }
  size_t eb = (size_t)b * E_ENC;
  enc_mean[eb + tid]       = m0 * (1.f / 64.f);
  enc_mean[eb + tid + 256] = m1 * (1.f / 64.f);
  enc_mean[eb + tid + 512] = m2 * (1.f / 64.f);
  enc_mean[eb + tid + 768] = m3 * (1.f / 64.f);

  {
    int t = tid >> 2, part = tid & 3;
    const float* r = fb + t * E_ENC + part * 256;
    const float* wp = wv + part * 256;
    float s = 0.f;
    for (int e = 0; e < 256; e += 4) {
      float4 f4 = *(const float4*)(r + e);
      float4 w4 = *(const float4*)(wp + e);
      s += f4.x * w4.x + f4.y * w4.y + f4.z * w4.z + f4.w * w4.w;
    }
    s += __shfl_xor(s, 1);
    s += __shfl_xor(s, 2);
    if (part == 0) s_attw[t] = s + c0[0];
  }
  __syncthreads();
  if (tid < 64) {
    float v = s_attw[tid];
    float mx = v;
    #pragma unroll
    for (int off = 32; off > 0; off >>= 1) mx = fmaxf(mx, __shfl_xor(mx, off));
    float e = expf(v - mx);
    float sm = e;
    #pragma unroll
    for (int off = 32; off > 0; off >>= 1) sm += __shfl_xor(sm, off);
    s_attw[tid] = e / sm;
  }
  __syncthreads();
  float ca = 0, cb = 0, cc = 0, cd = 0;
  for (int t = 0; t < T; ++t) {
    float w = s_attw[t];
    const float* r = fb + t * E_ENC;
    ca += w * r[tid]; cb += w * r[tid + 256]; cc += w * r[tid + 512]; cd += w * r[tid + 768];
  }
  ctxb[eb + tid]       = f2bf(ca);
  ctxb[eb + tid + 256] = f2bf(cb);
  ctxb[eb + tid + 512] = f2bf(cc);
  ctxb[eb + tid + 768] = f2bf(cd);
}

// ---------------------------------------------------------------------------
// base1[b,d] = b1[d] + enc_mean[b,:1024] . W1[d,:1024]
__global__ void k_base1(const float* __restrict__ enc_mean, const float* __restrict__ W1,
                        const float* __restrict__ b1, float* __restrict__ base1) {
  __shared__ float em[E_ENC];
  int b = blockIdx.x, tid = threadIdx.x;
  for (int i = tid; i < E_ENC; i += 256) em[i] = enc_mean[(size_t)b * E_ENC + i];
  __syncthreads();
  for (int d = tid; d < D; d += 256) {
    const float* w = W1 + (size_t)d * (E_ENC + EMB);
    float acc = 0.f;
    for (int e = 0; e < E_ENC; e += 4) {
      float4 w4 = *(const float4*)(w + e);
      acc += w4.x * em[e] + w4.y * em[e + 1] + w4.z * em[e + 2] + w4.w * em[e + 3];
    }
    base1[b * D + d] = acc + b1[d];
  }
}

// ---------------------------------------------------------------------------
// Gather embedding rows per caption token -> bf16 Xe[2048][512]
__global__ void k_gather_emb(const float* __restrict__ embed_W,
                             const int* __restrict__ captions,
                             unsigned short* __restrict__ Xe) {
  int g = blockIdx.x, tid = threadIdx.x;
  int cap = captions[g];
  const float* src = embed_W + (size_t)cap * EMB;
  float2 v = *(const float2*)(src + tid * 2);
  unsigned int pk = (unsigned int)f2bf(v.x) | ((unsigned int)f2bf(v.y) << 16);
  *(unsigned int*)(Xe + (size_t)g * EMB + tid * 2) = pk;
}

// W1 decode-half conversion: w1db[d][c] = bf16(W1[d][1024+c])
__global__ void k_cvt_w1d(const float* __restrict__ W1, unsigned short* __restrict__ w1db) {
  int d = blockIdx.x, tid = threadIdx.x;
  float2 v = *(const float2*)(W1 + (size_t)d * (E_ENC + EMB) + E_ENC + tid * 2);
  unsigned int pk = (unsigned int)f2bf(v.x) | ((unsigned int)f2bf(v.y) << 16);
  *(unsigned int*)(w1db + (size_t)d * EMB + tid * 2) = pk;
}

// ---------------------------------------------------------------------------
// x1 GEMM: x1[g][d] = base1[g>>5][d] + Xe[g,:] . w1db[d,:]   M=2048,N=512,K=512
__global__ __launch_bounds__(256) void k_x1_mfma(
    const unsigned short* __restrict__ Xe, const unsigned short* __restrict__ w1db,
    const float* __restrict__ base1, float* __restrict__ x1) {
  __shared__ __align__(16) unsigned short As[64 * 64];  // 8 KB
  __shared__ __align__(16) unsigned short Bs[64 * 64];  // 8 KB
  int c0 = blockIdx.x * 64, g0 = blockIdx.y * 64;
  int tid = threadIdx.x, lane = tid & 63, wave = tid >> 6;
  int wr = wave >> 1, wc = wave & 1;
  int rsel = lane & 15, hi = lane >> 4;

  f32x4 acc[2][2];
  #pragma unroll
  for (int m = 0; m < 2; ++m)
    #pragma unroll
    for (int n = 0; n < 2; ++n) acc[m][n] = (f32x4){0.f, 0.f, 0.f, 0.f};

  int r1 = tid >> 3, s1 = tid & 7;
  int sw = (s1 ^ (r1 & 7)) * 8;
  const unsigned short* gA1 = Xe + (size_t)(g0 + r1) * EMB + sw;
  const unsigned short* gA2 = Xe + (size_t)(g0 + r1 + 32) * EMB + sw;
  const unsigned short* gB1 = w1db + (size_t)(c0 + r1) * EMB + sw;
  const unsigned short* gB2 = w1db + (size_t)(c0 + r1 + 32) * EMB + sw;
  unsigned short* aD1 = As + wave * 512;
  unsigned short* aD2 = As + 2048 + wave * 512;
  unsigned short* bD1 = Bs + wave * 512;
  unsigned short* bD2 = Bs + 2048 + wave * 512;

  int slot0 = hi ^ (rsel & 7);
  int slot1 = (4 + hi) ^ (rsel & 7);

  for (int kt = 0; kt < EMB / 64; ++kt) {
    gload_lds16(gA1, aD1);
    gload_lds16(gA2, aD2);
    gload_lds16(gB1, bD1);
    gload_lds16(gB2, bD2);
    gA1 += 64; gA2 += 64; gB1 += 64; gB2 += 64;
    __syncthreads();

    bf16x8 af[2][2], bfr[2][2];
    #pragma unroll
    for (int m = 0; m < 2; ++m) {
      int rowA = (wr * 32 + m * 16 + rsel) * 64;
      af[m][0] = *(const bf16x8*)(As + rowA + slot0 * 8);
      af[m][1] = *(const bf16x8*)(As + rowA + slot1 * 8);
    }
    #pragma unroll
    for (int n = 0; n < 2; ++n) {
      int rowB = (wc * 32 + n * 16 + rsel) * 64;
      bfr[n][0] = *(const bf16x8*)(Bs + rowB + slot0 * 8);
      bfr[n][1] = *(const bf16x8*)(Bs + rowB + slot1 * 8);
    }
    #pragma unroll
    for (int m = 0; m < 2; ++m)
      #pragma unroll
      for (int n = 0; n < 2; ++n) {
        acc[m][n] = __builtin_amdgcn_mfma_f32_16x16x32_bf16(af[m][0], bfr[n][0], acc[m][n], 0, 0, 0);
        acc[m][n] = __builtin_amdgcn_mfma_f32_16x16x32_bf16(af[m][1], bfr[n][1], acc[m][n], 0, 0, 0);
      }
    __syncthreads();
  }

  #pragma unroll
  for (int m = 0; m < 2; ++m)
    #pragma unroll
    for (int i = 0; i < 4; ++i) {
      int g = g0 + wr * 32 + m * 16 + hi * 4 + i;
      const float* br = base1 + (size_t)(g >> 5) * D;
      float* xr = x1 + (size_t)g * D;
      #pragma unroll
      for (int n = 0; n < 2; ++n) {
        int c = c0 + wc * 32 + n * 16 + rsel;
        xr[c] = acc[m][n][i] + br[c];
      }
    }
}

// ---------------------------------------------------------------------------
// im2col: Xc[g][k*512+dp] = (l+k-6 >= 0) ? x[b][l+k-6][dp] : 0   (bf16)
__global__ void k_im2col(const float* __restrict__ x, unsigned short* __restrict__ Xc) {
  int g = blockIdx.x, tid = threadIdx.x;
  int b = g >> 5, l = g & 31;
  unsigned short* row = Xc + (size_t)g * KC;
  const float* xb = x + (size_t)b * L * D;
  int d = tid * 2;
  #pragma unroll
  for (int k = 0; k < KSZ; ++k) {
    int lp = l + k - 6;
    unsigned int pk = 0;
    if (lp >= 0) {
      float2 v = *(const float2*)(xb + (size_t)lp * D + d);
      pk = (unsigned int)f2bf(v.x) | ((unsigned int)f2bf(v.y) << 16);
    }
    *(unsigned int*)(row + k * 512 + d) = pk;
  }
}

// ---------------------------------------------------------------------------
// conv weight reorder+convert: wb[c][k*512+dp] = bf16(w[c][dp*7+k])
__global__ void k_cvt_wconv(const float* __restrict__ w, unsigned short* __restrict__ wb) {
  __shared__ float row[KC];  // 14 KiB
  int c = blockIdx.x, tid = threadIdx.x;
  const float* wr = w + (size_t)c * KC;
  for (int i = tid; i < KC; i += 256) row[i] = wr[i];
  __syncthreads();
  unsigned short* ob = wb + (size_t)c * KC;
  int dp = tid * 2;
  #pragma unroll
  for (int k = 0; k < KSZ; ++k) {
    unsigned int pk = (unsigned int)f2bf(row[dp * 7 + k]) |
                      ((unsigned int)f2bf(row[(dp + 1) * 7 + k]) << 16);
    *(unsigned int*)(ob + k * 512 + dp) = pk;
  }
}

// ---------------------------------------------------------------------------
// Conv GEMM: y[g][c] = bias[c] + Xc[g,:] . wb[c,:]   M=2048, N=1024, K=3584
// Tile 128g x 64c, BK=64, 4 waves (2x2), 4x2 frags/wave. XOR slot swizzle.
// 1-D grid 256 blocks with XCD-bijective remap (c-tile fastest within chunk)
// so each XCD owns 2 g-tiles: A fetched once chip-wide.
__global__ __launch_bounds__(256) void k_conv_mfma(
    const unsigned short* __restrict__ Xc, const unsigned short* __restrict__ wb,
    const float* __restrict__ bias, float* __restrict__ y) {
  __shared__ __align__(16) unsigned short As[128 * 64];  // 16 KB
  __shared__ __align__(16) unsigned short Bs[64 * 64];   // 8 KB
  int flat = blockIdx.x;                 // 256 = 8 * 32
  int ord = (flat & 7) * 32 + (flat >> 3);
  int c0 = (ord & 15) * 64, g0 = (ord >> 4) * 128;
  int tid = threadIdx.x, lane = tid & 63, wave = tid >> 6;
  int wr = wave >> 1, wc = wave & 1;
  int rsel = lane & 15, hi = lane >> 4;

  f32x4 acc[4][2];
  #pragma unroll
  for (int m = 0; m < 4; ++m)
    #pragma unroll
    for (int n = 0; n < 2; ++n) acc[m][n] = (f32x4){0.f, 0.f, 0.f, 0.f};

  int r0 = tid >> 3, slot = tid & 7;
  int swseg = (slot ^ (r0 & 7)) * 8;     // (r0+32p)&7 == r0&7
  const unsigned short* gA[4];
  const unsigned short* gB[2];
  #pragma unroll
  for (int p = 0; p < 4; ++p)
    gA[p] = Xc + (size_t)(g0 + r0 + 32 * p) * KC + swseg;
  #pragma unroll
  for (int p = 0; p < 2; ++p)
    gB[p] = wb + (size_t)(c0 + r0 + 32 * p) * KC + swseg;

  for (int kt = 0; kt < KC / 64; ++kt) {
    #pragma unroll
    for (int p = 0; p < 4; ++p) {
      gload_lds16(gA[p], As + p * 2048 + wave * 512);
      gA[p] += 64;
    }
    #pragma unroll
    for (int p = 0; p < 2; ++p) {
      gload_lds16(gB[p], Bs + p * 2048 + wave * 512);
      gB[p] += 64;
    }
    __syncthreads();

    bf16x8 af[4][2], bfr[2][2];
    #pragma unroll
    for (int m = 0; m < 4; ++m) {
      int rowA = (wr * 64 + m * 16 + rsel) * 64;
      #pragma unroll
      for (int kk = 0; kk < 2; ++kk)
        af[m][kk] = *(const bf16x8*)(As + rowA + (((kk * 4 + hi) ^ (rsel & 7)) * 8));
    }
    #pragma unroll
    for (int n = 0; n < 2; ++n) {
      int rowB = (wc * 32 + n * 16 + rsel) * 64;
      #pragma unroll
      for (int kk = 0; kk < 2; ++kk)
        bfr[n][kk] = *(const bf16x8*)(Bs + rowB + (((kk * 4 + hi) ^ (rsel & 7)) * 8));
    }
    #pragma unroll
    for (int kk = 0; kk < 2; ++kk)
      #pragma unroll
      for (int m = 0; m < 4; ++m)
        #pragma unroll
        for (int n = 0; n < 2; ++n)
          acc[m][n] = __builtin_amdgcn_mfma_f32_16x16x32_bf16(af[m][kk], bfr[n][kk], acc[m][n], 0, 0, 0);
    __syncthreads();
  }

  float bv[2];
  #pragma unroll
  for (int n = 0; n < 2; ++n) bv[n] = bias[c0 + wc * 32 + n * 16 + rsel];
  #pragma unroll
  for (int m = 0; m < 4; ++m)
    #pragma unroll
    for (int i = 0; i < 4; ++i) {
      int g = g0 + wr * 64 + m * 16 + hi * 4 + i;
      float* yr = y + (size_t)g * 1024;
      #pragma unroll
      for (int n = 0; n < 2; ++n)
        yr[c0 + wc * 32 + n * 16 + rsel] = acc[m][n][i] + bv[n];
    }
}

// ---------------------------------------------------------------------------
// GLU: xout[g][d] = y[g][d] * sigmoid(y[g][d+512]) + xres[g][d]
__global__ void k_glu(const float* __restrict__ y, const float* __restrict__ xres,
                      float* __restrict__ xout) {
  int idx = blockIdx.x * 256 + threadIdx.x;  // 2048*128
  int g = idx >> 7, d4 = (idx & 127) << 2;
  const float* yr = y + (size_t)g * 1024;
  float4 a = *(const float4*)(yr + d4);
  float4 bq = *(const float4*)(yr + 512 + d4);
  float4 xr = *(const float4*)(xres + (size_t)g * 512 + d4);
  float4 o;
  o.x = a.x / (1.f + expf(-bq.x)) + xr.x;
  o.y = a.y / (1.f + expf(-bq.y)) + xr.y;
  o.z = a.z / (1.f + expf(-bq.z)) + xr.z;
  o.w = a.w / (1.f + expf(-bq.w)) + xr.w;
  *(float4*)(xout + (size_t)g * 512 + d4) = o;
}

// Layer-2 GLU: writes bf16 x3 directly.
__global__ void k_glu_bf16(const float* __restrict__ y, const float* __restrict__ xres,
                           unsigned short* __restrict__ xout) {
  int idx = blockIdx.x * 256 + threadIdx.x;
  int g = idx >> 7, d4 = (idx & 127) << 2;
  const float* yr = y + (size_t)g * 1024;
  float4 a = *(const float4*)(yr + d4);
  float4 bq = *(const float4*)(yr + 512 + d4);
  float4 xr = *(const float4*)(xres + (size_t)g * 512 + d4);
  ushort4 o;
  o.x = f2bf(a.x / (1.f + expf(-bq.x)) + xr.x);
  o.y = f2bf(a.y / (1.f + expf(-bq.y)) + xr.y);
  o.z = f2bf(a.z / (1.f + expf(-bq.z)) + xr.z);
  o.w = f2bf(a.w / (1.f + expf(-bq.w)) + xr.w);
  *(ushort4*)(xout + (size_t)g * 512 + d4) = o;
}

// ---------------------------------------------------------------------------
// cbase[b,v] = b2[v] + ctx[b,:1024] . W2[v,:1024]  as bf16 MFMA.
__global__ __launch_bounds__(256) void k_cbase_mfma(
    const unsigned short* __restrict__ ctxb,  // [64][1024] bf16
    const float* __restrict__ W2,             // [30000][1536] fp32
    const float* __restrict__ b2, float* __restrict__ cbase) {
  __shared__ __align__(16) unsigned short As[64 * 64];    // 8 KB
  __shared__ __align__(16) unsigned short Bs[128 * 64];   // 16 KB
  int v0 = blockIdx.x * 128;
  int tid = threadIdx.x, lane = tid & 63, wave = tid >> 6;
  int rsel = lane & 15, hi = lane >> 4;
  int wc = wave;

  f32x4 acc[4][2];
  #pragma unroll
  for (int m = 0; m < 4; ++m)
    #pragma unroll
    for (int n = 0; n < 2; ++n) acc[m][n] = (f32x4){0.f, 0.f, 0.f, 0.f};

  int ra1 = tid >> 3, sa = tid & 7;
  int ra2 = ra1 + 32;
  const unsigned short* gA1 = ctxb + (size_t)ra1 * 1024 + (sa ^ (ra1 & 7)) * 8;
  const unsigned short* gA2 = ctxb + (size_t)ra2 * 1024 + (sa ^ (ra2 & 7)) * 8;
  unsigned short* aD1 = As + wave * 512;
  unsigned short* aD2 = As + 2048 + wave * 512;

  const float* gB[4];
  int bofs[4];
  #pragma unroll
  for (int p = 0; p < 4; ++p) {
    int row = p * 32 + (tid >> 3);
    int seg = tid & 7;
    int vr = v0 + row; if (vr > V - 1) vr = V - 1;
    gB[p] = W2 + (size_t)vr * (E_ENC + D) + seg * 8;
    bofs[p] = row * 64 + (seg ^ (row & 7)) * 8;
  }

  for (int kt = 0; kt < 16; ++kt) {
    gload_lds16(gA1, aD1);
    gload_lds16(gA2, aD2);
    gA1 += 64; gA2 += 64;
    #pragma unroll
    for (int p = 0; p < 4; ++p) {
      float4 f0 = *(const float4*)(gB[p]);
      float4 f1 = *(const float4*)(gB[p] + 4);
      gB[p] += 64;
      bf16x8 o;
      o[0] = (short)f2bf(f0.x); o[1] = (short)f2bf(f0.y);
      o[2] = (short)f2bf(f0.z); o[3] = (short)f2bf(f0.w);
      o[4] = (short)f2bf(f1.x); o[5] = (short)f2bf(f1.y);
      o[6] = (short)f2bf(f1.z); o[7] = (short)f2bf(f1.w);
      *(bf16x8*)(Bs + bofs[p]) = o;
    }
    __syncthreads();

    bf16x8 af[4][2], bfr[2][2];
    #pragma unroll
    for (int m = 0; m < 4; ++m) {
      int rowA = (m * 16 + rsel) * 64;
      #pragma unroll
      for (int kk = 0; kk < 2; ++kk)
        af[m][kk] = *(const bf16x8*)(As + rowA + ((kk * 4 + hi) ^ (rsel & 7)) * 8);
    }
    #pragma unroll
    for (int n = 0; n < 2; ++n) {
      int rowB = (wc * 32 + n * 16 + rsel) * 64;
      #pragma unroll
      for (int kk = 0; kk < 2; ++kk)
        bfr[n][kk] = *(const bf16x8*)(Bs + rowB + ((kk * 4 + hi) ^ (rsel & 7)) * 8);
    }
    #pragma unroll
    for (int kk = 0; kk < 2; ++kk)
      #pragma unroll
      for (int m = 0; m < 4; ++m)
        #pragma unroll
        for (int n = 0; n < 2; ++n)
          acc[m][n] = __builtin_amdgcn_mfma_f32_16x16x32_bf16(af[m][kk], bfr[n][kk], acc[m][n], 0, 0, 0);
    __syncthreads();
  }

  #pragma unroll
  for (int n = 0; n < 2; ++n) {
    int v = v0 + wc * 32 + n * 16 + rsel;
    if (v >= V) continue;
    float bias = b2[v];
    #pragma unroll
    for (int m = 0; m < 4; ++m)
      #pragma unroll
      for (int i = 0; i < 4; ++i) {
        int b = m * 16 + hi * 4 + i;
        cbase[(size_t)b * V + v] = acc[m][n][i] + bias;
      }
  }
}

// ---------------------------------------------------------------------------
// W2 decode-half conversion: y[v][c] = bf16(W2[v][1024+c])
__global__ void k_cvt_w2d(const float* __restrict__ W2, unsigned short* __restrict__ y) {
  int i = blockIdx.x * 256 + threadIdx.x;   // 30000*128 groups of 4
  int row = i >> 7, c = (i & 127) << 2;
  float4 f = *(const float4*)(W2 + (size_t)row * (E_ENC + D) + E_ENC + c);
  ushort4 o;
  o.x = f2bf(f.x); o.y = f2bf(f.y); o.z = f2bf(f.z); o.w = f2bf(f.w);
  *(ushort4*)(y + (size_t)row * D + c) = o;
}

// ---------------------------------------------------------------------------
// logits[b,s,v] = cbase[b,v] + x3[b,s,:] . W2d[v,:]
// M=2048, N=30000, K=512. Tile 128g x 128v, BK=64, 4 waves (2x2), 4x4 frags.
// XOR slot swizzle (conflict-free ds_read_b128) + XCD-bijective remap
// (3760 = 8*470; all 16 g-tiles of a v-tile land on one XCD -> W2d L2 reuse).
__global__ __launch_bounds__(256) void k_logits_mfma(
    const unsigned short* __restrict__ Ab,   // x3 bf16 [2048][512]
    const unsigned short* __restrict__ Bb,   // W2d bf16 [30000][512]
    const float* __restrict__ cbase, float* __restrict__ out) {
  __shared__ __align__(16) unsigned short As[128 * 64];  // 16 KB
  __shared__ __align__(16) unsigned short Bs[128 * 64];  // 16 KB
  int flat = blockIdx.x;                  // 3760 = 8 * 470
  int ord = (flat & 7) * 470 + (flat >> 3);
  int v0 = (ord >> 4) * 128, g0 = (ord & 15) * 128;
  int tid = threadIdx.x, lane = tid & 63, wave = tid >> 6;
  int wr = wave >> 1, wc = wave & 1;
  int rsel = lane & 15, hi = lane >> 4;

  f32x4 acc[4][4];
  #pragma unroll
  for (int m = 0; m < 4; ++m)
    #pragma unroll
    for (int n = 0; n < 4; ++n) acc[m][n] = (f32x4){0.f, 0.f, 0.f, 0.f};

  int r0 = tid >> 3, slot = tid & 7;
  int swseg = (slot ^ (r0 & 7)) * 8;      // (r0+32p)&7 == r0&7 (local-row swizzle)
  const unsigned short* gA[4];
  const unsigned short* gB[4];
  #pragma unroll
  for (int p = 0; p < 4; ++p) {
    gA[p] = Ab + (size_t)(g0 + r0 + 32 * p) * 512 + swseg;
    int rB = v0 + r0 + 32 * p; if (rB > V - 1) rB = V - 1;
    gB[p] = Bb + (size_t)rB * 512 + swseg;
  }

  for (int kt = 0; kt < 8; ++kt) {
    #pragma unroll
    for (int p = 0; p < 4; ++p) {
      gload_lds16(gA[p], As + p * 2048 + wave * 512);
      gload_lds16(gB[p], Bs + p * 2048 + wave * 512);
      gA[p] += 64; gB[p] += 64;
    }
    __syncthreads();

    bf16x8 af[4][2], bfr[4][2];
    #pragma unroll
    for (int m = 0; m < 4; ++m) {
      int rowA = (wr * 64 + m * 16 + rsel) * 64;
      #pragma unroll
      for (int kk = 0; kk < 2; ++kk)
        af[m][kk] = *(const bf16x8*)(As + rowA + (((kk * 4 + hi) ^ (rsel & 7)) * 8));
    }
    #pragma unroll
    for (int n = 0; n < 4; ++n) {
      int rowB = (wc * 64 + n * 16 + rsel) * 64;
      #pragma unroll
      for (int kk = 0; kk < 2; ++kk)
        bfr[n][kk] = *(const bf16x8*)(Bs + rowB + (((kk * 4 + hi) ^ (rsel & 7)) * 8));
    }
    #pragma unroll
    for (int kk = 0; kk < 2; ++kk)
      #pragma unroll
      for (int m = 0; m < 4; ++m)
        #pragma unroll
        for (int n = 0; n < 4; ++n)
          acc[m][n] = __builtin_amdgcn_mfma_f32_16x16x32_bf16(af[m][kk], bfr[n][kk], acc[m][n], 0, 0, 0);
    __syncthreads();
  }

  #pragma unroll
  for (int m = 0; m < 4; ++m) {
    #pragma unroll
    for (int i = 0; i < 4; ++i) {
      int g = g0 + wr * 64 + m * 16 + hi * 4 + i;
      int b = g >> 5, lt = g & 31;
      if (lt >= S) continue;
      size_t orow = ((size_t)b * S + lt) * V;
      const float* cb = cbase + (size_t)b * V;
      #pragma unroll
      for (int n = 0; n < 4; ++n) {
        int v = v0 + wc * 64 + n * 16 + rsel;
        if (v < V) out[orow + v] = acc[m][n][i] + cb[v];
      }
    }
  }
}

// ---------------------------------------------------------------------------
extern "C" void kernel_launch(void* const* d_in, const int* in_sizes, int n_in,
                              void* d_out, int out_size, void* d_ws, size_t ws_size,
                              hipStream_t stream) {
  const float* features = (const float*)d_in[0];
  const int*   captions = (const int*)d_in[1];
  const float* embed_W  = (const float*)d_in[3];
  const float* W1   = (const float*)d_in[4];
  const float* b1   = (const float*)d_in[5];
  const float* cw1  = (const float*)d_in[6];
  const float* cb1  = (const float*)d_in[7];
  const float* cw2  = (const float*)d_in[8];
  const float* cb2  = (const float*)d_in[9];
  const float* Wenc = (const float*)d_in[10];
  const float* benc = (const float*)d_in[11];
  const float* Wp   = (const float*)d_in[14];
  const float* W2   = (const float*)d_in[16];
  const float* b2   = (const float*)d_in[17];
  float* out = (float*)d_out;

  float* ws = (float*)d_ws;
  float* wv       = ws;                 // 1024
  float* c0       = ws + 1024;          // 16
  float* enc_mean = ws + 1040;          // 65536
  unsigned short* ctxb = (unsigned short*)(ws + 66576);  // 65536 bf16
  float* base1    = ws + 132112;        // 32768
  float* xA       = ws + 164880;        // 1048576 (x1; dead after GLU1)
  float* xB       = ws + 1213456;       // 1048576 (x2)
  float* y        = ws + 2262032;       // 2097152 (conv GEMM out; cbase aliases)
  float* cbase    = y;                  // 1920000 <= 2097152
  unsigned short* x3b  = (unsigned short*)xA;             // 1048576 bf16 (xA dead)
  unsigned short* Xc   = (unsigned short*)(ws + 4359184); // 7340032 bf16
  unsigned short* wbuf = (unsigned short*)(ws + 8029200); // 3670016 bf16
  unsigned short* W2d  = (unsigned short*)(ws + 9864208); // 15360000 bf16
  // Xe / w1db live inside the Xc region (free until im2col layer 1)
  unsigned short* Xe   = Xc;                 // 1048576 bf16
  unsigned short* w1db = Xc + 1048576;       // 262144 bf16
  // end: 17,544,208 floats = 70.2 MB (unchanged)

  hipLaunchKernelGGL(k_cvt_w2d,  dim3(15000),   dim3(256), 0, stream, W2, W2d);
  hipLaunchKernelGGL(k_wv,       dim3(4),       dim3(256), 0, stream, Wenc, Wp, benc, wv, c0);
  hipLaunchKernelGGL(k_mean_ctx, dim3(B),       dim3(256), 0, stream, features, wv, c0, enc_mean, ctxb);
  hipLaunchKernelGGL(k_base1,    dim3(B),       dim3(256), 0, stream, enc_mean, W1, b1, base1);

  // x1 = base1 + emb @ W1decᵀ  (MFMA)
  hipLaunchKernelGGL(k_gather_emb, dim3(2048),  dim3(256), 0, stream, embed_W, captions, Xe);
  hipLaunchKernelGGL(k_cvt_w1d,    dim3(512),   dim3(256), 0, stream, W1, w1db);
  hipLaunchKernelGGL(k_x1_mfma,    dim3(8, 32), dim3(256), 0, stream, Xe, w1db, base1, xA);

  // conv layer 1
  hipLaunchKernelGGL(k_cvt_wconv, dim3(1024),   dim3(256), 0, stream, cw1, wbuf);
  hipLaunchKernelGGL(k_im2col,    dim3(2048),   dim3(256), 0, stream, xA, Xc);
  hipLaunchKernelGGL(k_conv_mfma, dim3(256),    dim3(256), 0, stream, Xc, wbuf, cb1, y);
  hipLaunchKernelGGL(k_glu,       dim3(1024),   dim3(256), 0, stream, y, xA, xB);

  // conv layer 2
  hipLaunchKernelGGL(k_cvt_wconv, dim3(1024),   dim3(256), 0, stream, cw2, wbuf);
  hipLaunchKernelGGL(k_im2col,    dim3(2048),   dim3(256), 0, stream, xB, Xc);
  hipLaunchKernelGGL(k_conv_mfma, dim3(256),    dim3(256), 0, stream, Xc, wbuf, cb2, y);
  hipLaunchKernelGGL(k_glu_bf16,  dim3(1024),   dim3(256), 0, stream, y, xB, x3b);

  hipLaunchKernelGGL(k_cbase_mfma, dim3(235),   dim3(256), 0, stream, ctxb, W2, b2, cbase);
  hipLaunchKernelGGL(k_logits_mfma, dim3(3760), dim3(256), 0, stream, x3b, W2d, cbase, out);
}